// Round 5
// baseline (71.992 us; speedup 1.0000x reference)
//
#include <hip/hip_runtime.h>

// Shapes fixed by the reference: bs=4, n=10, H=W=256.
constexpr int kN  = 10;        // planes
constexpr int kHW = 256 * 256;
constexpr int kBS = 4;

// One thread per pixel (262,144 threads = 4096 waves = 4 waves/SIMD — the
// problem-size TLP cap). Scalar f32 throughout: R4's packed-f32 variant was
// neutral-to-negative, reverted. All 20 global loads are hoisted ahead of
// any arithmetic so they issue back-to-back (single vmcnt drain) — the one
// exposed HBM-latency window is the only nontrivial kernel term left; the
// 268 MB workspace poison right before us flushes L3, so loads are cold.
//
// Bit-exactness contract (absmax == 0.0 in R1-R4 — preserve it):
//  * plane sums: left-associative sequential adds, prefix-shared with the
//    SAME association as the reference fold.
//  * x/10, x/9: (float)((double)x * RN(1/10 or 1/9)) — proven identical to
//    correctly-rounded fp32 division (f64 product rel-err <= 2.3e-16 vs
//    >= ~8e-10 relative distance of any quotient to an fp32 midpoint).
//  * (v-mean)^2: separate sub/mul/add under fp contract(off) — no FMA.
//  * sqrtf: correctly-rounded fp32 sqrt (default HIP, no fast-math).
//  * argmin: strict <, first occurrence, split order 0..10.
// DO NOT: var-based argmin, raw v_sqrt_f32, algebraic var expansion, FMA
// contraction — each risks argmin tie-flips worth ~0.1 vs threshold 3.8e-2
// (expected O(1..10) flipped pixels at 262k — one flip fails the bench).
__global__ __launch_bounds__(256) void distreg_kernel(
    const float* __restrict__ s1, const float* __restrict__ blur,
    float* __restrict__ out) {
  #pragma clang fp contract(off)
  const int g = blockIdx.x * blockDim.x + threadIdx.x;  // pixel id
  const int b = g >> 16;        // kHW == 65536
  const int r = g & (kHW - 1);

  const long base = (long)b * kN * kHW + r;
  const float* __restrict__ ps = s1 + base;
  const float* __restrict__ pb = blur + base;

  // Hoist ALL global loads first — no arithmetic between them.
  float sv[kN], bv[kN];
  #pragma unroll
  for (int j = 0; j < kN; ++j) sv[j] = ps[(long)j * kHW];
  #pragma unroll
  for (int j = 0; j < kN; ++j) bv[j] = pb[(long)j * kHW];

  float lo[kN], hi[kN];
  #pragma unroll
  for (int j = 0; j < kN; ++j) {
    lo[j] = sv[j] - bv[j];   // used for j >= split i
    hi[j] = sv[j] + bv[j];   // used for j <  split i
  }

  float best_sd   = __builtin_inff();
  float best_mean = 0.0f;
  float p = 0.0f;               // prefix: hi[0] + ... + hi[i-1], left-assoc
  #pragma unroll
  for (int i = 0; i <= kN; ++i) {
    // sum_i = ((p + lo[i]) + lo[i+1]) + ... — same association as reference.
    float sum = p;
    #pragma unroll
    for (int j = 0; j < kN; ++j) if (j >= i) sum = sum + lo[j];
    const float mean = (float)((double)sum * 0.1);      // == sum / 10.0f

    float sq = 0.0f;
    #pragma unroll
    for (int j = 0; j < kN; ++j) {
      const float v  = (j < i) ? hi[j] : lo[j];         // static select
      const float x  = v - mean;
      const float xx = x * x;    // contract(off): stays a separate mul
      sq = sq + xx;
    }
    const float var = (float)((double)sq * (1.0 / 9.0)); // == sq / 9.0f
    const float sd  = sqrtf(var);

    if (sd < best_sd) { best_sd = sd; best_mean = mean; } // first occurrence
    if (i < kN) p = p + hi[i];
  }

  out[(long)b * kHW + r] = best_mean;
}

extern "C" void kernel_launch(void* const* d_in, const int* in_sizes, int n_in,
                              void* d_out, int out_size, void* d_ws, size_t ws_size,
                              hipStream_t stream) {
  const float* s1   = (const float*)d_in[0];
  const float* blur = (const float*)d_in[1];
  float* out = (float*)d_out;

  const int total = kBS * kHW;            // 262,144 pixels
  const int block = 256;
  const int grid  = total / block;        // 1024 blocks
  distreg_kernel<<<grid, block, 0, stream>>>(s1, blur, out);
}